// Round 12
// baseline (406.887 us; speedup 1.0000x reference)
//
#include <hip/hip_runtime.h>
#include <stdint.h>

typedef unsigned short u16;
typedef unsigned long long u64;
typedef __attribute__((ext_vector_type(8))) short s8v;
typedef __attribute__((ext_vector_type(4))) float f4v;

#define MFMA(a, b, c) __builtin_amdgcn_mfma_f32_16x16x32_bf16((a), (b), (c), 0, 0, 0)

__device__ __forceinline__ u16 f2b(float f) {
  uint32_t x = __float_as_uint(f);
  x += 0x7fff + ((x >> 16) & 1);   // RNE
  return (u16)(x >> 16);
}
__device__ __forceinline__ float b2f(u16 u) {
  return __uint_as_float(((uint32_t)u) << 16);
}

// async global->LDS, 16B per lane. LDS dest must be wave-uniform base + lane*16.
__device__ __forceinline__ void gll16(const void* g, void* l) {
  __builtin_amdgcn_global_load_lds((const __attribute__((address_space(1))) uint32_t*)g,
                                   (__attribute__((address_space(3))) uint32_t*)l, 16, 0, 0);
}
__device__ __forceinline__ void bar() { __builtin_amdgcn_s_barrier(); }

// ---------------- fused fp32 -> bf16 convert (all 5 tensors, one dispatch) ----------------
__global__ void cvt_all(const float* __restrict__ x, const float* __restrict__ wq,
                        const float* __restrict__ wk, const float* __restrict__ wv,
                        const float* __restrict__ wo,
                        u16* __restrict__ xb, u16* __restrict__ wqkv, u16* __restrict__ wob) {
  int i = blockIdx.x * 256 + threadIdx.x;   // 8-elem chunk index
  const float* s; u16* d; size_t off;
  if      (i < 1048576) { s = x;  d = xb;   off = (size_t)i; }
  else if (i < 3145728) { s = wq; d = wqkv; off = (size_t)(i - 1048576); }
  else if (i < 3670016) { s = wk; d = wqkv + (size_t)16777216; off = (size_t)(i - 3145728); }
  else if (i < 4194304) { s = wv; d = wqkv + (size_t)20971520; off = (size_t)(i - 3670016); }
  else                  { s = wo; d = wob;  off = (size_t)(i - 4194304); }
  const float4* sp = (const float4*)(s + off * 8);
  float4 f0 = sp[0], f1 = sp[1];
  s8v o;
  o[0] = (short)f2b(f0.x); o[1] = (short)f2b(f0.y); o[2] = (short)f2b(f0.z); o[3] = (short)f2b(f0.w);
  o[4] = (short)f2b(f1.x); o[5] = (short)f2b(f1.y); o[6] = (short)f2b(f1.z); o[7] = (short)f2b(f1.w);
  *(s8v*)(d + off * 8) = o;
}

// ---------------- 4-phase GEMM, BN=128, 2 blocks/CU, weights-as-A ----------------
// A = weights [F][K], B = activations [2048][K]. C[feat][tok] = A·B^T + bias.
// 8 waves (2M x 4N), wave tile (BM/2) x 32. BK=64, dbuf LDS (80/64 KB -> 2 blocks/CU).
// Ledger (uniform for NH=2,3): counted vmcnt(2) at phi2/phi4 drains the oldest
// loads = {B-cur 2, A-cur NH}; leaves next-B 2 in flight. B-odd staged at phi4-prev.
// Last iter: drains to 0. All LDS WARs >=1 barrier after reads.
template <int BM, int MODE>
__global__ __launch_bounds__(512, 4) void gemm4p(
    const u16* __restrict__ A, const u16* __restrict__ Bact,
    const float* __restrict__ bias,
    float* __restrict__ Cf, u16* __restrict__ Cq, u16* __restrict__ Ck, u16* __restrict__ Cv,
    int K) {
  extern __shared__ u16 smem[];
  constexpr int AO = BM * 64;          // A-odd elem offset
  constexpr int BE = 2 * BM * 64;      // B-even
  constexpr int BO = BE + 128 * 64;    // B-odd
  constexpr int MI = BM / 64;          // A frags per quadrant (qr)
  constexpr int NH = BM / 64;          // A staging glls per slot

  const int tid = threadIdx.x;
  const int l = tid & 63, wv = tid >> 6;
  const int wm = wv >> 2, wn = wv & 3;
  const int lr = l & 15, lg = l >> 4;
  const int swz = 16 * (lr & 7);
  const int wrow = wm * (BM / 2);

  // XCD-aware swizzle, m-major logical order
  const int nwg = gridDim.x;
  int bid = blockIdx.x;
  bid = (bid & 7) * (nwg >> 3) + (bid >> 3);
  const int NB = 16;                   // 2048 tokens / 128
  const int m0 = (bid / NB) * BM, n0 = (bid % NB) * 128;

  const size_t K64 = (size_t)64 * K;

  const int sr = tid >> 3;
  const int sc = ((tid & 7) ^ (sr & 7)) * 8;
  const u16* gA = A + (size_t)(m0 + sr) * K + sc;
  const u16* gB = Bact + (size_t)(n0 + sr) * K + sc;

  auto STA = [&](int P, int h, int kt) {   // stage A rows [64h, 64h+64)
    gll16(gA + (size_t)(h * 64) * K + (size_t)kt * 64,
          smem + (P ? AO : 0) + h * 4096 + tid * 8);
  };
  auto STB = [&](int P, int kt) {          // stage whole 128-row B tile (2 glls)
    const u16* g = gB + (size_t)kt * 64;
    u16* d = smem + (P ? BO : BE) + tid * 8;
    gll16(g, d);
    gll16(g + K64, d + 4096);
  };

  const char* smc = (const char*)smem;
  s8v a[MI][2], b0[2][2], b1[2][2];
  auto LDA = [&](int P, int QR) {
#pragma unroll
    for (int mi = 0; mi < MI; ++mi)
#pragma unroll
      for (int kk = 0; kk < 2; ++kk)
        a[mi][kk] = *(const s8v*)(smc + (P ? AO * 2 : 0) +
            (wrow + QR * (BM / 4) + mi * 16 + lr) * 128 + ((kk * 64 + lg * 16) ^ swz));
  };
  auto LDB = [&](int P, s8v bb[2][2]) {
#pragma unroll
    for (int ni = 0; ni < 2; ++ni)
#pragma unroll
      for (int kk = 0; kk < 2; ++kk)
        bb[ni][kk] = *(const s8v*)(smc + (P ? BO * 2 : BE * 2) +
            (wn * 32 + ni * 16 + lr) * 128 + ((kk * 64 + lg * 16) ^ swz));
  };

  f4v acc[2 * MI][2];
#pragma unroll
  for (int i = 0; i < 2 * MI; ++i)
#pragma unroll
    for (int j = 0; j < 2; ++j) acc[i][j] = {0.f, 0.f, 0.f, 0.f};

#define PHMF(QR, B)                                                            \
  __builtin_amdgcn_s_setprio(1);                                               \
  _Pragma("unroll") for (int mi = 0; mi < MI; ++mi)                            \
    _Pragma("unroll") for (int ni = 0; ni < 2; ++ni)                           \
      _Pragma("unroll") for (int kk = 0; kk < 2; ++kk)                         \
        acc[(QR) * MI + mi][ni] =                                              \
            MFMA(a[mi][kk], B[ni][kk], acc[(QR) * MI + mi][ni]);               \
  __builtin_amdgcn_s_setprio(0);

  // prologue: A-even (NH) + B-even (2) + B-odd (2); drain first NH+2, leave B-odd 2
#pragma unroll
  for (int h = 0; h < NH; ++h) STA(0, h, 0);
  STB(0, 0);
  STB(1, 1);
  asm volatile("s_waitcnt vmcnt(2)" ::: "memory");
  bar();

  const int ITERS = K >> 7;
  for (int i = 0; i < ITERS; ++i) {
    const int kn = 2 * i + 2;
    const bool more = (i + 1 < ITERS);
    // phi1: even tile qr0; stage A-odd h0,h1
    LDA(0, 0); LDB(0, b0);
    STA(1, 0, 2 * i + 1); STA(1, 1, 2 * i + 1);
    bar(); PHMF(0, b0); bar();
    // phi2: even tile qr1; stage rest A-odd + B-even(next); counted wait
    LDA(0, 1);
    if constexpr (NH > 2) STA(1, 2, 2 * i + 1);
    if (more) STB(0, kn);
    bar(); PHMF(1, b0);
    if (more) asm volatile("s_waitcnt vmcnt(2)" ::: "memory");
    else      asm volatile("s_waitcnt vmcnt(0)" ::: "memory");
    bar();
    // phi3: odd tile qr0; stage A-even(next) h0,h1
    LDA(1, 0); LDB(1, b1);
    if (more) { STA(0, 0, kn); STA(0, 1, kn); }
    bar(); PHMF(0, b1); bar();
    // phi4: odd tile qr1; stage rest A-even(next) + B-odd(next); counted wait
    LDA(1, 1);
    if (more) {
      if constexpr (NH > 2) STA(0, 2, kn);
      STB(1, 2 * i + 3);
    }
    bar(); PHMF(1, b1);
    if (more) asm volatile("s_waitcnt vmcnt(2)" ::: "memory");
    else      asm volatile("s_waitcnt vmcnt(0)" ::: "memory");
    bar();
  }
#undef PHMF

  bar();   // all loop LDS reads done; smem reusable as epilogue scratch

  if constexpr (MODE == 2) {
    // V stripes (feat >= 5120): feature-major direct write
#pragma unroll
    for (int ai = 0; ai < 2 * MI; ++ai) {
      const int f0 = m0 + wrow + ai * 16;
      if (f0 >= 5120) {
#pragma unroll
        for (int ni = 0; ni < 2; ++ni)
#pragma unroll
          for (int r = 0; r < 4; ++r) {
            const int f = f0 + lg * 4 + r;
            const int tok = n0 + wn * 32 + ni * 16 + lr;
            Cv[(size_t)(f - 5120) * 2048 + tok] = f2b(acc[ai][ni][r] + bias[f]);
          }
      }
    }
    // Q/K stripes: token-major via per-wave LDS transpose (single pass, 32 tok/wave)
    if (m0 + wrow < 5120) {
      u16* buf = smem + wv * 3328;     // [32 tok][104 feats]
#pragma unroll
      for (int ni = 0; ni < 2; ++ni) {
        const int tl = ni * 16 + lr;
#pragma unroll
        for (int ai = 0; ai < 2 * MI; ++ai) {
          const int f0 = m0 + wrow + ai * 16;
          if (f0 < 5120) {
#pragma unroll
            for (int r = 0; r < 4; ++r) {
              const int fl = ai * 16 + lg * 4 + r;
              buf[tl * 104 + fl] = f2b(acc[ai][ni][r] + bias[m0 + wrow + fl]);
            }
          }
        }
      }
      asm volatile("s_waitcnt lgkmcnt(0)" ::: "memory");
      const int row = l >> 1, half = l & 1;
      const int tok = n0 + wn * 32 + row;
#pragma unroll
      for (int i2 = 0; i2 < 6; ++i2) {
        const int flc = (2 * i2 + half) * 8;       // 16B-aligned chunk
        const int f = m0 + wrow + flc;
        if (f < 4096)
          *(s8v*)(Cq + (size_t)tok * 4096 + f) = *(const s8v*)(buf + row * 104 + flc);
        else if (f < 5120)
          *(s8v*)(Ck + (size_t)tok * 1024 + (f - 4096)) = *(const s8v*)(buf + row * 104 + flc);
      }
      asm volatile("s_waitcnt lgkmcnt(0)" ::: "memory");
    }
  } else {
    // fp32 out[tok][4096] via per-wave LDS transpose (32 tok/wave, 2 passes)
    float* buf = (float*)smem + wv * 1088;   // [16 tok][68 feat]
#pragma unroll
    for (int c = 0; c < 2; ++c) {
#pragma unroll
      for (int ai = 0; ai < 2 * MI; ++ai)
#pragma unroll
        for (int r = 0; r < 4; ++r) {
          const int fl = ai * 16 + lg * 4 + r;
          buf[lr * 68 + fl] = acc[ai][c][r] + bias[m0 + wrow + fl];
        }
      asm volatile("s_waitcnt lgkmcnt(0)" ::: "memory");
      const int row = l >> 2, q4 = l & 3;
      const int tok = n0 + wn * 32 + c * 16 + row;
      float* g = Cf + (size_t)tok * 4096 + m0 + wrow + q4 * 16;
      const float* src = buf + row * 68 + q4 * 16;
#pragma unroll
      for (int i2 = 0; i2 < 4; ++i2)
        *(f4v*)(g + i2 * 4) = *(const f4v*)(src + i2 * 4);
      asm volatile("s_waitcnt lgkmcnt(0)" ::: "memory");
    }
  }
}

// ---------------- RoPE (in place on bf16 q,k) ----------------
__global__ void rope_kernel(u16* __restrict__ q, u16* __restrict__ k, const int* __restrict__ pos) {
  int i = blockIdx.x * 256 + threadIdx.x;
  const int NQ = 2048 * 32 * 64;
  const int NK = 2048 * 8 * 64;
  u16* buf;
  int m, d, stride, h;
  if (i < NQ) { buf = q; m = i >> 11; h = (i >> 6) & 31; d = i & 63; stride = 4096; }
  else {
    i -= NQ; if (i >= NK) return;
    buf = k; m = i >> 9; h = (i >> 6) & 7; d = i & 63; stride = 1024;
  }
  size_t base = (size_t)m * stride + h * 128 + d;
  float a = b2f(buf[base]), b = b2f(buf[base + 64]);
  float p = (float)pos[m];
  float ang = p * exp2f(-0.20762050593045952f * (float)d);
  float s, c;
  sincosf(ang, &s, &c);
  buf[base]      = f2b(a * c - b * s);
  buf[base + 64] = f2b(b * c + a * s);
}

// ---------------- flash attention (dbuf K/V via __syncthreads full-drain) ----------------
__global__ __launch_bounds__(512, 4) void attn_kernel(const u16* __restrict__ Q, const u16* __restrict__ Kb,
                                                      const u16* __restrict__ Vt, u16* __restrict__ Ao) {
  __shared__ __align__(16) u16 Ks[2][64 * 128];
  __shared__ __align__(16) u16 Vs[2][128 * 64];
  __shared__ __align__(16) u16 Ps[8][16 * 64];
  const int tid = threadIdx.x;
  const int l = tid & 63, wv = tid >> 6;
  const int lr = l & 15, lg = l >> 4;
  const int head = blockIdx.x >> 4, qt = blockIdx.x & 15;
  const int kh = head >> 2;
  const int qrow = qt * 128 + wv * 16 + lr;

  s8v qf[4];
#pragma unroll
  for (int s = 0; s < 4; ++s)
    qf[s] = *(const s8v*)&Q[(size_t)qrow * 4096 + head * 128 + s * 32 + lg * 8];

  f4v zero = {0.f, 0.f, 0.f, 0.f};
  f4v ao[8];
#pragma unroll
  for (int tt = 0; tt < 8; ++tt) ao[tt] = zero;
  float mrun = -1e30f, lrun = 0.f;

  const int ki0 = tid, ki1 = tid + 512;
  const int kr0 = ki0 >> 4, kc0 = (ki0 & 15) ^ (kr0 & 7);
  const int kr1 = ki1 >> 4, kc1 = (ki1 & 15) ^ (kr1 & 7);
  const int vr0 = ki0 >> 3, vc0 = (ki0 & 7) ^ (vr0 & 7);
  const int vr1 = ki1 >> 3, vc1 = (ki1 & 7) ^ (vr1 & 7);
  const u16* Kg = Kb + kh * 128;
  const u16* Vg = Vt + (size_t)(kh * 128) * 2048;
  const u16* kp0 = Kg + (size_t)kr0 * 1024 + kc0 * 8;
  const u16* kp1 = Kg + (size_t)kr1 * 1024 + kc1 * 8;
  const u16* vp0 = Vg + (size_t)vr0 * 2048 + vc0 * 8;
  const u16* vp1 = Vg + (size_t)vr1 * 2048 + vc1 * 8;

  auto stage = [&](int b, int t) {
    gll16(kp0 + (size_t)t * 1024, (char*)Ks[b] + ki0 * 16);
    gll16(kp1 + (size_t)t * 1024, (char*)Ks[b] + ki1 * 16);
    gll16(vp0 + t,                (char*)Vs[b] + ki0 * 16);
    gll16(vp1 + t,                (char*)Vs[b] + ki1 * 16);
  };

  char* PwB = (char*)Ps[wv];
  const int swz = 16 * (lr & 7);
  const float C2 = 0.12753102f;         // (1/sqrt(128)) * log2(e)

  stage(0, 0);
  __syncthreads();

  for (int t = 0; t < 2048; t += 64) {
    const int cur = (t >> 6) & 1;
    if (t + 64 < 2048) stage(cur ^ 1, t + 64);
    const char* KsB = (const char*)Ks[cur];
    const char* VsB = (const char*)Vs[cur];

    f4v c[4];
#pragma unroll
    for (int j = 0; j < 4; ++j) c[j] = zero;
#pragma unroll
    for (int s = 0; s < 4; ++s) {
#pragma unroll
      for (int j = 0; j < 4; ++j) {
        s8v kf = *(const s8v*)(KsB + (16 * j + lr) * 256 + (((4 * s + lg) * 16) ^ swz));
        c[j] = MFMA(kf, qf[s], c[j]);
      }
    }

    float mx = fmaxf(fmaxf(c[0][0], c[0][1]), fmaxf(c[0][2], c[0][3]));
#pragma unroll
    for (int j = 1; j < 4; ++j)
      mx = fmaxf(mx, fmaxf(fmaxf(c[j][0], c[j][1]), fmaxf(c[j][2], c[j][3])));
    mx = fmaxf(mx, __shfl_xor(mx, 16));
    mx = fmaxf(mx, __shfl_xor(mx, 32));
    float m2x = mx * C2;

    if (!__all(m2x - mrun <= 8.f)) {      // defer-max
      float mnew = fmaxf(mrun, m2x);
      float alpha = __builtin_amdgcn_exp2f(mrun - mnew);
      float ar[4];
#pragma unroll
      for (int r = 0; r < 4; ++r) ar[r] = __shfl(alpha, 4 * lg + r);
#pragma unroll
      for (int tt = 0; tt < 8; ++tt)
#pragma unroll
        for (int r = 0; r < 4; ++r) ao[tt][r] *= ar[r];
      lrun *= alpha;
      mrun = mnew;
    }

    float rs = 0.f;
#pragma unroll
    for (int j = 0; j < 4; ++j) {
      float p0 = __builtin_amdgcn_exp2f(__builtin_fmaf(c[j][0], C2, -mrun));
      float p1 = __builtin_amdgcn_exp2f(__builtin_fmaf(c[j][1], C2, -mrun));
      float p2 = __builtin_amdgcn_exp2f(__builtin_fmaf(c[j][2], C2, -mrun));
      float p3 = __builtin_amdgcn_exp2f(__builtin_fmaf(c[j][3], C2, -mrun));
      rs += (p0 + p1) + (p2 + p3);
      uint32_t lo = (uint32_t)f2b(p0) | ((uint32_t)f2b(p1) << 16);
      uint32_t hi = (uint32_t)f2b(p2) | ((uint32_t)f2b(p3) << 16);
      u64 pak = (u64)lo | ((u64)hi << 32);
      *(u64*)(PwB + lr * 128 + ((32 * j + 8 * lg) ^ swz)) = pak;
    }
    rs += __shfl_xor(rs, 16);
    rs += __shfl_xor(rs, 32);
    lrun += rs;

#pragma unroll
    for (int h = 0; h < 2; ++h) {
      s8v pf = *(const s8v*)(PwB + lr * 128 + ((64 * h + 16 * lg) ^ swz));
#pragma unroll
      for (int tt = 0; tt < 8; ++tt) {
        s8v vf = *(const s8v*)(VsB + (16 * tt + lr) * 128 + (((4 * h + lg) * 16) ^ swz));
        ao[tt] = MFMA(pf, vf, ao[tt]);
      }
    }

    __syncthreads();
  }

  float inv = 1.f / lrun;
  float ir[4];
#pragma unroll
  for (int r = 0; r < 4; ++r) ir[r] = __shfl(inv, 4 * lg + r);
#pragma unroll
  for (int tt = 0; tt < 8; ++tt)
#pragma unroll
    for (int r = 0; r < 4; ++r)
      Ao[(size_t)(qt * 128 + wv * 16 + 4 * lg + r) * 4096 + head * 128 + 16 * tt + lr] =
          f2b(ao[tt][r] * ir[r]);
}

extern "C" void kernel_launch(void* const* d_in, const int* in_sizes, int n_in,
                              void* d_out, int out_size, void* d_ws, size_t ws_size,
                              hipStream_t stream) {
  const float* x  = (const float*)d_in[0];
  const int*   pos = (const int*)d_in[1];
  const float* wq = (const float*)d_in[2];
  const float* bq = (const float*)d_in[3];
  const float* wk = (const float*)d_in[4];
  const float* bk = (const float*)d_in[5];
  const float* wv = (const float*)d_in[6];
  const float* bv = (const float*)d_in[7];
  const float* wo = (const float*)d_in[8];
  const float* bo = (const float*)d_in[9];
  float* out = (float*)d_out;

  char* ws = (char*)d_ws;
  u16* xb   = (u16*)(ws + 0);           // 16 MB  x bf16 [2048][4096]
  u16* wqkv = (u16*)(ws + 16777216);    // 48 MB  wq|wk|wv bf16 [6144][4096]
  u16* wob  = (u16*)(ws + 67108864);    // 32 MB  wo bf16 [4096][4096]
  u16* qb   = (u16*)(ws + 100663296);   // 16 MB  q bf16 [2048][4096]
  u16* kb   = (u16*)(ws + 117440512);   //  4 MB  k bf16 [2048][1024]
  u16* vT   = (u16*)(ws + 121634816);   //  4 MB  v^T bf16 [1024][2048]
  u16* ab   = (u16*)(ws + 125829120);   // 16 MB  attn out bf16 [2048][4096]
  float* bqkv = (float*)(ws + 142606336); // 24 KB concat bias [6144] fp32

  hipMemcpyAsync(bqkv,        bq, 4096 * sizeof(float), hipMemcpyDeviceToDevice, stream);
  hipMemcpyAsync(bqkv + 4096, bk, 1024 * sizeof(float), hipMemcpyDeviceToDevice, stream);
  hipMemcpyAsync(bqkv + 5120, bv, 1024 * sizeof(float), hipMemcpyDeviceToDevice, stream);

  cvt_all<<<24576, 256, 0, stream>>>(x, wq, wk, wv, wo, xb, wqkv, wob);

  // QKV: BM=192 x BN=128 -> 32x16 = 512 blocks, 80 KB LDS -> 2 blocks/CU
  gemm4p<192, 2><<<512, 512, 81920, stream>>>(wqkv, xb, bqkv,
                                              nullptr, qb, kb, vT, 4096);
  rope_kernel<<<(2048 * 32 * 64 + 2048 * 8 * 64) / 256, 256, 0, stream>>>(qb, kb, pos);
  attn_kernel<<<512, 512, 0, stream>>>(qb, kb, vT, ab);
  // O-proj: BM=128 x BN=128 -> 32x16 = 512 blocks, 64 KB LDS -> 2 blocks/CU
  gemm4p<128, 0><<<512, 512, 65536, stream>>>(wob, ab, bo,
                                              out, nullptr, nullptr, nullptr, 4096);
}

// Round 13
// 325.609 us; speedup vs baseline: 1.2496x; 1.2496x over previous
//
#include <hip/hip_runtime.h>
#include <stdint.h>

typedef unsigned short u16;
typedef unsigned long long u64;
typedef __attribute__((ext_vector_type(8))) short s8v;
typedef __attribute__((ext_vector_type(4))) float f4v;

#define MFMA(a, b, c) __builtin_amdgcn_mfma_f32_16x16x32_bf16((a), (b), (c), 0, 0, 0)

__device__ __forceinline__ u16 f2b(float f) {
  uint32_t x = __float_as_uint(f);
  x += 0x7fff + ((x >> 16) & 1);   // RNE
  return (u16)(x >> 16);
}
__device__ __forceinline__ float b2f(u16 u) {
  return __uint_as_float(((uint32_t)u) << 16);
}

// async global->LDS, 16B per lane. LDS dest must be wave-uniform base + lane*16.
__device__ __forceinline__ void gll16(const void* g, void* l) {
  __builtin_amdgcn_global_load_lds((const __attribute__((address_space(1))) uint32_t*)g,
                                   (__attribute__((address_space(3))) uint32_t*)l, 16, 0, 0);
}
__device__ __forceinline__ void bar() { __builtin_amdgcn_s_barrier(); }

// ---------------- fused fp32 -> bf16 convert (all 5 tensors, one dispatch) ----------------
__global__ void cvt_all(const float* __restrict__ x, const float* __restrict__ wq,
                        const float* __restrict__ wk, const float* __restrict__ wv,
                        const float* __restrict__ wo,
                        u16* __restrict__ xb, u16* __restrict__ wqkv, u16* __restrict__ wob) {
  int i = blockIdx.x * 256 + threadIdx.x;   // 8-elem chunk index
  const float* s; u16* d; size_t off;
  if      (i < 1048576) { s = x;  d = xb;   off = (size_t)i; }
  else if (i < 3145728) { s = wq; d = wqkv; off = (size_t)(i - 1048576); }
  else if (i < 3670016) { s = wk; d = wqkv + (size_t)16777216; off = (size_t)(i - 3145728); }
  else if (i < 4194304) { s = wv; d = wqkv + (size_t)20971520; off = (size_t)(i - 3670016); }
  else                  { s = wo; d = wob;  off = (size_t)(i - 4194304); }
  const float4* sp = (const float4*)(s + off * 8);
  float4 f0 = sp[0], f1 = sp[1];
  s8v o;
  o[0] = (short)f2b(f0.x); o[1] = (short)f2b(f0.y); o[2] = (short)f2b(f0.z); o[3] = (short)f2b(f0.w);
  o[4] = (short)f2b(f1.x); o[5] = (short)f2b(f1.y); o[6] = (short)f2b(f1.z); o[7] = (short)f2b(f1.w);
  *(s8v*)(d + off * 8) = o;
}

// ---------------- 4-phase GEMM (r10 green), BN=256, weights-as-A ----------------
template <int BM, int MODE>
__global__ __launch_bounds__(512, 2) void gemm8p(
    const u16* __restrict__ A, const u16* __restrict__ Bact,
    const float* __restrict__ bias,
    float* __restrict__ Cf, u16* __restrict__ Cq, u16* __restrict__ Ck, u16* __restrict__ Cv,
    int K) {
  extern __shared__ u16 smem[];
  constexpr int AO = BM * 64;          // A-odd elem offset
  constexpr int BE = 2 * BM * 64;      // B-even
  constexpr int BO = BE + 16384;       // B-odd
  constexpr int MI = BM / 64;          // A frags per quadrant
  constexpr int NH = BM / 64;          // A staging rounds per slot (64 rows each)

  const int tid = threadIdx.x;
  const int l = tid & 63, wv = tid >> 6;
  const int wm = wv >> 2, wn = wv & 3;
  const int lr = l & 15, lg = l >> 4;
  const int swz = 16 * (lr & 7);
  const int wrow = wm * (BM / 2);

  const int nwg = gridDim.x;
  int bid = blockIdx.x;
  bid = (bid & 7) * (nwg >> 3) + (bid >> 3);
  const int NB = 8;                    // 2048 tokens / 256
  const int m0 = (bid / NB) * BM, n0 = (bid % NB) * 256;

  const size_t K64 = (size_t)64 * K;

  const int sr = tid >> 3;
  const int sc = ((tid & 7) ^ (sr & 7)) * 8;
  const u16* gA = A + (size_t)(m0 + sr) * K + sc;
  const u16* gB = Bact + (size_t)(n0 + sr) * K + sc;

  auto STA = [&](int P, int h, int kt) {   // stage A rows [64h, 64h+64)
    gll16(gA + (size_t)(h * 64) * K + (size_t)kt * 64,
          smem + (P ? AO : 0) + h * 4096 + tid * 8);
  };
  auto STB = [&](int P, int h, int kt) {   // stage B rows [128h, 128h+128)
    const u16* g = gB + (size_t)(h * 128) * K + (size_t)kt * 64;
    u16* d = smem + (P ? BO : BE) + h * 8192 + tid * 8;
    gll16(g, d);
    gll16(g + K64, d + 4096);
  };

  const char* smc = (const char*)smem;
  s8v a[MI][2], b0[2][2], b1[2][2];
  auto LDA = [&](int P, int QR) {
#pragma unroll
    for (int mi = 0; mi < MI; ++mi)
#pragma unroll
      for (int kk = 0; kk < 2; ++kk)
        a[mi][kk] = *(const s8v*)(smc + (P ? AO * 2 : 0) +
            (wrow + QR * (BM / 4) + mi * 16 + lr) * 128 + ((kk * 64 + lg * 16) ^ swz));
  };
  auto LDB = [&](int P, int QC, s8v bb[2][2]) {
#pragma unroll
    for (int ni = 0; ni < 2; ++ni)
#pragma unroll
      for (int kk = 0; kk < 2; ++kk)
        bb[ni][kk] = *(const s8v*)(smc + (P ? BO * 2 : BE * 2) +
            (wn * 64 + QC * 32 + ni * 16 + lr) * 128 + ((kk * 64 + lg * 16) ^ swz));
  };

  f4v acc[BM / 32][4];
#pragma unroll
  for (int i = 0; i < BM / 32; ++i)
#pragma unroll
    for (int j = 0; j < 4; ++j) acc[i][j] = {0.f, 0.f, 0.f, 0.f};

#define PHMF(QR, QC, B)                                                        \
  _Pragma("unroll") for (int mi = 0; mi < MI; ++mi)                            \
    _Pragma("unroll") for (int ni = 0; ni < 2; ++ni)                           \
      _Pragma("unroll") for (int kk = 0; kk < 2; ++kk)                         \
        acc[(QR) * MI + mi][(QC) * 2 + ni] =                                   \
            MFMA(a[mi][kk], B[ni][kk], acc[(QR) * MI + mi][(QC) * 2 + ni]);

  // prologue: even slot fully + odd B halves; leftover = 4 odd-B loads
  STB(0, 0, 0); STB(0, 1, 0);
#pragma unroll
  for (int h = 0; h < NH; ++h) STA(0, h, 0);
  STB(1, 0, 1); STB(1, 1, 1);
  asm volatile("s_waitcnt vmcnt(4)" ::: "memory");
  bar();

  const int ITERS = K >> 7;
  for (int i = 0; i < ITERS; ++i) {
    const int kn = 2 * i + 2;
    const bool more = (i + 1 < ITERS);
    // P1: even tile, qr0 x (qc0+qc1); stage A-odd rows 0..127
    LDA(0, 0); LDB(0, 0, b0); LDB(0, 1, b1);
    STA(1, 0, 2 * i + 1); STA(1, 1, 2 * i + 1);
    bar();
    __builtin_amdgcn_s_setprio(1);
    PHMF(0, 0, b0); PHMF(0, 1, b1);
    __builtin_amdgcn_s_setprio(0);
    bar();
    // P2: even tile, qr1; stage rest of A-odd + B-even(next); counted wait
    LDA(0, 1);
    if constexpr (NH > 2) STA(1, 2, 2 * i + 1);
    if (more) { STB(0, 0, kn); STB(0, 1, kn); }
    bar();
    __builtin_amdgcn_s_setprio(1);
    PHMF(1, 1, b1); PHMF(1, 0, b0);
    __builtin_amdgcn_s_setprio(0);
    if (more) asm volatile("s_waitcnt vmcnt(4)" ::: "memory");
    else      asm volatile("s_waitcnt vmcnt(0)" ::: "memory");
    bar();
    // P3: odd tile, qr0; stage A-even(next) rows 0..127
    LDA(1, 0); LDB(1, 0, b0); LDB(1, 1, b1);
    if (more) { STA(0, 0, kn); STA(0, 1, kn); }
    bar();
    __builtin_amdgcn_s_setprio(1);
    PHMF(0, 0, b0); PHMF(0, 1, b1);
    __builtin_amdgcn_s_setprio(0);
    bar();
    // P4: odd tile, qr1; stage rest A-even + B-odd(next); counted wait
    LDA(1, 1);
    if (more) {
      if constexpr (NH > 2) STA(0, 2, kn);
      STB(1, 0, 2 * i + 3); STB(1, 1, 2 * i + 3);
    }
    bar();
    __builtin_amdgcn_s_setprio(1);
    PHMF(1, 1, b1); PHMF(1, 0, b0);
    __builtin_amdgcn_s_setprio(0);
    asm volatile("s_waitcnt vmcnt(4)" ::: "memory");
    bar();
  }
#undef PHMF

  bar();   // LDS now reusable as epilogue scratch

  if constexpr (MODE == 2) {
    // V stripes (feat >= 5120): feature-major direct write
#pragma unroll
    for (int fi = 0; fi < BM / 32; ++fi) {
      const int f0 = m0 + wrow + fi * 16;
      if (f0 >= 5120) {
#pragma unroll
        for (int fj = 0; fj < 4; ++fj)
#pragma unroll
          for (int r = 0; r < 4; ++r) {
            const int f = f0 + lg * 4 + r;
            const int tok = n0 + wn * 64 + fj * 16 + lr;
            Cv[(size_t)(f - 5120) * 2048 + tok] = f2b(acc[fi][fj][r] + bias[f]);
          }
      }
    }
    // Q/K stripes: token-major via per-wave LDS transpose
    if (m0 + wrow < 5120) {
      u16* buf = smem + wv * 3328;     // [32 tok][104 feats]
#pragma unroll
      for (int c = 0; c < 2; ++c) {
#pragma unroll
        for (int fj2 = 0; fj2 < 2; ++fj2) {
          const int fj = 2 * c + fj2;
          const int tl = fj2 * 16 + lr;
#pragma unroll
          for (int fi = 0; fi < BM / 32; ++fi) {
            const int f0 = m0 + wrow + fi * 16;
            if (f0 < 5120) {
#pragma unroll
              for (int r = 0; r < 4; ++r) {
                const int fl = fi * 16 + lg * 4 + r;
                buf[tl * 104 + fl] = f2b(acc[fi][fj][r] + bias[m0 + wrow + fl]);
              }
            }
          }
        }
        asm volatile("s_waitcnt lgkmcnt(0)" ::: "memory");
        const int row = l >> 1, half = l & 1;
        const int tok = n0 + wn * 64 + c * 32 + row;
#pragma unroll
        for (int i2 = 0; i2 < 6; ++i2) {
          const int flc = (2 * i2 + half) * 8;       // 16B-aligned chunk
          const int f = m0 + wrow + flc;
          if (f < 4096)
            *(s8v*)(Cq + (size_t)tok * 4096 + f) = *(const s8v*)(buf + row * 104 + flc);
          else if (f < 5120)
            *(s8v*)(Ck + (size_t)tok * 1024 + (f - 4096)) = *(const s8v*)(buf + row * 104 + flc);
        }
        asm volatile("s_waitcnt lgkmcnt(0)" ::: "memory");
        bar();
      }
    } else {
      bar(); bar();   // keep barrier counts uniform across the block
    }
  } else {
    // fp32 out[tok][4096] via per-wave LDS transpose
    float* buf = (float*)smem + wv * 1088;   // [16 tok][68 feat]
#pragma unroll
    for (int c = 0; c < 4; ++c) {
#pragma unroll
      for (int fi = 0; fi < BM / 32; ++fi)
#pragma unroll
        for (int r = 0; r < 4; ++r) {
          const int fl = fi * 16 + lg * 4 + r;
          buf[lr * 68 + fl] = acc[fi][c][r] + bias[m0 + wrow + fl];
        }
      asm volatile("s_waitcnt lgkmcnt(0)" ::: "memory");
      const int row = l >> 2, q4 = l & 3;
      const int tok = n0 + wn * 64 + c * 16 + row;
      float* g = Cf + (size_t)tok * 4096 + m0 + wrow + q4 * 16;
      const float* src = buf + row * 68 + q4 * 16;
#pragma unroll
      for (int i2 = 0; i2 < 4; ++i2)
        *(f4v*)(g + i2 * 4) = *(const f4v*)(src + i2 * 4);
      asm volatile("s_waitcnt lgkmcnt(0)" ::: "memory");
    }
  }
}

// ---------------- RoPE (in place on bf16 q,k) ----------------
__global__ void rope_kernel(u16* __restrict__ q, u16* __restrict__ k, const int* __restrict__ pos) {
  int i = blockIdx.x * 256 + threadIdx.x;
  const int NQ = 2048 * 32 * 64;
  const int NK = 2048 * 8 * 64;
  u16* buf;
  int m, d, stride, h;
  if (i < NQ) { buf = q; m = i >> 11; h = (i >> 6) & 31; d = i & 63; stride = 4096; }
  else {
    i -= NQ; if (i >= NK) return;
    buf = k; m = i >> 9; h = (i >> 6) & 7; d = i & 63; stride = 1024;
  }
  size_t base = (size_t)m * stride + h * 128 + d;
  float a = b2f(buf[base]), b = b2f(buf[base + 64]);
  float p = (float)pos[m];
  float ang = p * exp2f(-0.20762050593045952f * (float)d);
  float s, c;
  sincosf(ang, &s, &c);
  buf[base]      = f2b(a * c - b * s);
  buf[base + 64] = f2b(b * c + a * s);
}

// ---------------- flash attention: 4 waves x 32 q-rows, sbuf K/V ----------------
// grid: 32 heads x 16 q-tiles(128 rows). 256 threads. Each wave owns 32 q rows
// (2 x 16-row halves) -> K/V fragment reads amortized over 2x MFMAs (LDS-BW fix).
// 48 KB LDS -> 3 blocks/CU; staging drained by __syncthreads, TLP hides bubbles.
__global__ __launch_bounds__(256, 2) void attn_kernel(const u16* __restrict__ Q, const u16* __restrict__ Kb,
                                                      const u16* __restrict__ Vt, u16* __restrict__ Ao) {
  __shared__ __align__(16) u16 Ks[64 * 128];
  __shared__ __align__(16) u16 Vs[128 * 64];
  __shared__ __align__(16) u16 Ps[4][32 * 64];
  const int tid = threadIdx.x;
  const int l = tid & 63, wv = tid >> 6;
  const int lr = l & 15, lg = l >> 4;
  const int head = blockIdx.x >> 4, qt = blockIdx.x & 15;
  const int kh = head >> 2;
  const int qrow = qt * 128 + wv * 32 + lr;

  s8v qf[2][4];
#pragma unroll
  for (int qh = 0; qh < 2; ++qh)
#pragma unroll
    for (int s = 0; s < 4; ++s)
      qf[qh][s] = *(const s8v*)&Q[(size_t)(qrow + qh * 16) * 4096 + head * 128 + s * 32 + lg * 8];

  f4v zero = {0.f, 0.f, 0.f, 0.f};
  f4v ao[2][8];
#pragma unroll
  for (int qh = 0; qh < 2; ++qh)
#pragma unroll
    for (int tt = 0; tt < 8; ++tt) ao[qh][tt] = zero;
  float mrun[2] = {-1e30f, -1e30f}, lrun[2] = {0.f, 0.f};

  // staging: 4 K-chunks + 4 V-chunks per thread (16 KB each tile)
  const u16* Kg = Kb + kh * 128;
  const u16* Vg = Vt + (size_t)(kh * 128) * 2048;
  const u16* kp[4];
  const u16* vp[4];
#pragma unroll
  for (int p = 0; p < 4; ++p) {
    const int ki = tid + 256 * p;
    const int kr = ki >> 4, kc = (ki & 15) ^ (kr & 7);
    kp[p] = Kg + (size_t)kr * 1024 + kc * 8;
    const int vr = ki >> 3, vc = (ki & 7) ^ (vr & 7);
    vp[p] = Vg + (size_t)vr * 2048 + vc * 8;
  }

  char* KsB = (char*)Ks;
  char* VsB = (char*)Vs;
  char* PwB = (char*)Ps[wv];
  const int swz = 16 * (lr & 7);
  const float C2 = 0.12753102f;         // (1/sqrt(128)) * log2(e)

  for (int t = 0; t < 2048; t += 64) {
    __syncthreads();
#pragma unroll
    for (int p = 0; p < 4; ++p) {
      gll16(kp[p] + (size_t)t * 1024, KsB + (tid + 256 * p) * 16);
      gll16(vp[p] + t,                VsB + (tid + 256 * p) * 16);
    }
    __syncthreads();

    // QK^T swapped, both q-halves share every K fragment
    f4v c[2][4];
#pragma unroll
    for (int qh = 0; qh < 2; ++qh)
#pragma unroll
      for (int j = 0; j < 4; ++j) c[qh][j] = zero;
#pragma unroll
    for (int s = 0; s < 4; ++s) {
#pragma unroll
      for (int j = 0; j < 4; ++j) {
        s8v kf = *(const s8v*)(KsB + (16 * j + lr) * 256 + (((4 * s + lg) * 16) ^ swz));
        c[0][j] = MFMA(kf, qf[0][s], c[0][j]);
        c[1][j] = MFMA(kf, qf[1][s], c[1][j]);
      }
    }

#pragma unroll
    for (int qh = 0; qh < 2; ++qh) {
      float mx = fmaxf(fmaxf(c[qh][0][0], c[qh][0][1]), fmaxf(c[qh][0][2], c[qh][0][3]));
#pragma unroll
      for (int j = 1; j < 4; ++j)
        mx = fmaxf(mx, fmaxf(fmaxf(c[qh][j][0], c[qh][j][1]), fmaxf(c[qh][j][2], c[qh][j][3])));
      mx = fmaxf(mx, __shfl_xor(mx, 16));
      mx = fmaxf(mx, __shfl_xor(mx, 32));
      float m2x = mx * C2;

      if (!__all(m2x - mrun[qh] <= 8.f)) {      // defer-max
        float mnew = fmaxf(mrun[qh], m2x);
        float alpha = __builtin_amdgcn_exp2f(mrun[qh] - mnew);
        float ar[4];
#pragma unroll
        for (int r = 0; r < 4; ++r) ar[r] = __shfl(alpha, 4 * lg + r);
#pragma unroll
        for (int tt = 0; tt < 8; ++tt)
#pragma unroll
          for (int r = 0; r < 4; ++r) ao[qh][tt][r] *= ar[r];
        lrun[qh] *= alpha;
        mrun[qh] = mnew;
      }

      float rs = 0.f;
#pragma unroll
      for (int j = 0; j < 4; ++j) {
        float p0 = __builtin_amdgcn_exp2f(__builtin_fmaf(c[qh][j][0], C2, -mrun[qh]));
        float p1 = __builtin_amdgcn_exp2f(__builtin_fmaf(c[qh][j][1], C2, -mrun[qh]));
        float p2 = __builtin_amdgcn_exp2f(__builtin_fmaf(c[qh][j][2], C2, -mrun[qh]));
        float p3 = __builtin_amdgcn_exp2f(__builtin_fmaf(c[qh][j][3], C2, -mrun[qh]));
        rs += (p0 + p1) + (p2 + p3);
        uint32_t lo = (uint32_t)f2b(p0) | ((uint32_t)f2b(p1) << 16);
        uint32_t hi = (uint32_t)f2b(p2) | ((uint32_t)f2b(p3) << 16);
        u64 pak = (u64)lo | ((u64)hi << 32);
        *(u64*)(PwB + (qh * 16 + lr) * 128 + ((32 * j + 8 * lg) ^ swz)) = pak;
      }
      rs += __shfl_xor(rs, 16);
      rs += __shfl_xor(rs, 32);
      lrun[qh] += rs;
    }

    // PV: both q-halves share every V fragment
#pragma unroll
    for (int h = 0; h < 2; ++h) {
      s8v pf0 = *(const s8v*)(PwB + lr * 128 + ((64 * h + 16 * lg) ^ swz));
      s8v pf1 = *(const s8v*)(PwB + (16 + lr) * 128 + ((64 * h + 16 * lg) ^ swz));
#pragma unroll
      for (int tt = 0; tt < 8; ++tt) {
        s8v vf = *(const s8v*)(VsB + (16 * tt + lr) * 128 + (((4 * h + lg) * 16) ^ swz));
        ao[0][tt] = MFMA(pf0, vf, ao[0][tt]);
        ao[1][tt] = MFMA(pf1, vf, ao[1][tt]);
      }
    }
  }

#pragma unroll
  for (int qh = 0; qh < 2; ++qh) {
    float inv = 1.f / lrun[qh];
    float ir[4];
#pragma unroll
    for (int r = 0; r < 4; ++r) ir[r] = __shfl(inv, 4 * lg + r);
#pragma unroll
    for (int tt = 0; tt < 8; ++tt)
#pragma unroll
      for (int r = 0; r < 4; ++r)
        Ao[(size_t)(qt * 128 + wv * 32 + qh * 16 + 4 * lg + r) * 4096 + head * 128 + 16 * tt + lr] =
            f2b(ao[qh][tt][r] * ir[r]);
  }
}

extern "C" void kernel_launch(void* const* d_in, const int* in_sizes, int n_in,
                              void* d_out, int out_size, void* d_ws, size_t ws_size,
                              hipStream_t stream) {
  const float* x  = (const float*)d_in[0];
  const int*   pos = (const int*)d_in[1];
  const float* wq = (const float*)d_in[2];
  const float* bq = (const float*)d_in[3];
  const float* wk = (const float*)d_in[4];
  const float* bk = (const float*)d_in[5];
  const float* wv = (const float*)d_in[6];
  const float* bv = (const float*)d_in[7];
  const float* wo = (const float*)d_in[8];
  const float* bo = (const float*)d_in[9];
  float* out = (float*)d_out;

  char* ws = (char*)d_ws;
  u16* xb   = (u16*)(ws + 0);           // 16 MB  x bf16 [2048][4096]
  u16* wqkv = (u16*)(ws + 16777216);    // 48 MB  wq|wk|wv bf16 [6144][4096]
  u16* wob  = (u16*)(ws + 67108864);    // 32 MB  wo bf16 [4096][4096]
  u16* qb   = (u16*)(ws + 100663296);   // 16 MB  q bf16 [2048][4096]
  u16* kb   = (u16*)(ws + 117440512);   //  4 MB  k bf16 [2048][1024]
  u16* vT   = (u16*)(ws + 121634816);   //  4 MB  v^T bf16 [1024][2048]
  u16* ab   = (u16*)(ws + 125829120);   // 16 MB  attn out bf16 [2048][4096]
  float* bqkv = (float*)(ws + 142606336); // 24 KB concat bias [6144] fp32

  hipMemcpyAsync(bqkv,        bq, 4096 * sizeof(float), hipMemcpyDeviceToDevice, stream);
  hipMemcpyAsync(bqkv + 4096, bk, 1024 * sizeof(float), hipMemcpyDeviceToDevice, stream);
  hipMemcpyAsync(bqkv + 5120, bv, 1024 * sizeof(float), hipMemcpyDeviceToDevice, stream);

  cvt_all<<<24576, 256, 0, stream>>>(x, wq, wk, wv, wo, xb, wqkv, wob);

  // QKV: A = wqkv [6144][4096], B = x [2048][4096]; BM=192 -> 32x8 = 256 blocks
  gemm8p<192, 2><<<256, 512, 114688, stream>>>(wqkv, xb, bqkv,
                                               nullptr, qb, kb, vT, 4096);
  rope_kernel<<<(2048 * 32 * 64 + 2048 * 8 * 64) / 256, 256, 0, stream>>>(qb, kb, pos);
  attn_kernel<<<512, 256, 0, stream>>>(qb, kb, vT, ab);
  // O-proj: A = wo [4096][4096], B = ab [2048][4096], fp32 out; 32x8 = 256 blocks
  gemm8p<128, 0><<<256, 512, 98304, stream>>>(wob, ab, bo,
                                              out, nullptr, nullptr, nullptr, 4096);
}